// Round 2
// baseline (685.507 us; speedup 1.0000x reference)
//
#include <hip/hip_runtime.h>

#define Bb 2
#define Ss 2048
#define Dd 1024
#define Hh 16
#define HD 64
#define Mm (Bb*Ss)   // 4096

typedef __bf16 bf16;
typedef __bf16 bf16x8 __attribute__((ext_vector_type(8)));
typedef __bf16 bf16x4 __attribute__((ext_vector_type(4)));
typedef float f32x4 __attribute__((ext_vector_type(4)));

// async global->LDS 16B copy (m97 pattern): LDS dest = base + lane*16
__device__ __forceinline__ void gl2lds(const bf16* g, bf16* l) {
    __builtin_amdgcn_global_load_lds((const __attribute__((address_space(1))) unsigned int*)g,
                                     (__attribute__((address_space(3))) unsigned int*)l, 16, 0, 0);
}

// ---------------- prep: fp32 -> bf16 cast ----------------
__global__ void cvt_f32_bf16(const float* __restrict__ in, bf16* __restrict__ out, int n4) {
    int i = blockIdx.x * blockDim.x + threadIdx.x;
    if (i < n4) {
        float4 v = *(const float4*)(in + i * 4);
        out[i*4+0] = (bf16)v.x; out[i*4+1] = (bf16)v.y;
        out[i*4+2] = (bf16)v.z; out[i*4+3] = (bf16)v.w;
    }
}

// ---------------- prep: W [K,N] fp32 -> Wt [N,K] bf16 ----------------
__global__ void wtrans(const float* __restrict__ W0, const float* __restrict__ W1,
                       const float* __restrict__ W2, const float* __restrict__ W3,
                       bf16* __restrict__ O0, bf16* __restrict__ O1,
                       bf16* __restrict__ O2, bf16* __restrict__ O3) {
    const float* W = (blockIdx.z == 0) ? W0 : (blockIdx.z == 1) ? W1 : (blockIdx.z == 2) ? W2 : W3;
    bf16* O = (blockIdx.z == 0) ? O0 : (blockIdx.z == 1) ? O1 : (blockIdx.z == 2) ? O2 : O3;
    __shared__ bf16 t[64][65];
    int k0 = blockIdx.x * 64, n0 = blockIdx.y * 64;
    for (int c = threadIdx.x; c < 4096; c += 256) {
        int r = c >> 6, cc = c & 63;
        t[r][cc] = (bf16)W[(k0 + r) * Dd + n0 + cc];
    }
    __syncthreads();
    for (int c = threadIdx.x; c < 4096; c += 256) {
        int r = c >> 6, cc = c & 63;
        O[(n0 + r) * Dd + k0 + cc] = t[cc][r];
    }
}

// ---------------- prep: concat biases ----------------
__global__ void bcat(const float* __restrict__ bq, const float* __restrict__ bk,
                     const float* __restrict__ bv, float* __restrict__ o) {
    int i = blockIdx.x * 256 + threadIdx.x;
    const float* s = (i < 1024) ? bq : (i < 2048) ? bk : bv;
    o[i] = s[i & 1023];
}

// ---------------- prep: V [b,h,s,d] -> Vt [b,h,d,s] ----------------
__global__ void vtrans(const bf16* __restrict__ Vw, bf16* __restrict__ Vt) {
    int st = blockIdx.x, h = blockIdx.y, b = blockIdx.z;
    __shared__ bf16 t[64][65];
    const bf16* src = Vw + ((size_t)(b * Hh + h) * Ss + st * 64) * HD;
    bf16* dst = Vt + (size_t)(b * Hh + h) * HD * Ss + st * 64;
    for (int c = threadIdx.x; c < 4096; c += 256) {
        int r = c >> 6, cc = c & 63;
        t[r][cc] = src[r * HD + cc];
    }
    __syncthreads();
    for (int c = threadIdx.x; c < 4096; c += 256) {
        int r = c >> 6, cc = c & 63;
        dst[(size_t)r * Ss + cc] = t[cc][r];
    }
}

// ---------------- GEMM v2: C[M,N] = A[M,K]*Bt[N,K]^T + bias, async LDS staging ----
// BM=128, BK=32. MODE 0: plain out [M,1024]. MODE 1: N=3072 merged QKV ->
// [b,h,s,hd] per sel, Q scaled by 0.125.
template<int BN, int MODE>
__global__ __launch_bounds__(256, 2)
void gemm2(const bf16* __restrict__ A, const bf16* __restrict__ Bt,
           const float* __restrict__ bias, bf16* __restrict__ outp) {
    const int K = 1024;
    __shared__ __align__(16) bf16 As[128 * 32];
    __shared__ __align__(16) bf16 Bs[BN * 32];
    int tid = threadIdx.x, wave = tid >> 6, lane = tid & 63;
    int lane15 = lane & 15, quad = lane >> 4;
    int m0 = blockIdx.x * 128, n0 = blockIdx.y * BN;
    int sr = lane >> 2, sc8 = (lane & 3) * 8;

    const bf16* Aga = A + (size_t)(m0 + wave * 32 + sr) * K + sc8;
    const bf16* Agb = Aga + (size_t)16 * K;
    bf16* lA0 = As + (wave * 32) * 32;
    bf16* lA1 = As + (wave * 32 + 16) * 32;

    const bf16* Bga; const bf16* Bgb = nullptr;
    bf16* lB0; bf16* lB1 = nullptr;
    if constexpr (BN == 128) {
        Bga = Bt + (size_t)(n0 + wave * 32 + sr) * K + sc8;
        Bgb = Bga + (size_t)16 * K;
        lB0 = Bs + (wave * 32) * 32;
        lB1 = Bs + (wave * 32 + 16) * 32;
    } else {
        Bga = Bt + (size_t)(n0 + wave * 16 + sr) * K + sc8;
        lB0 = Bs + (wave * 16) * 32;
    }

    constexpr int NI = (BN == 128) ? 4 : 2;
    const int WM = (BN == 128) ? ((wave >> 1) * 64) : (wave * 32);
    const int WN = (BN == 128) ? ((wave & 1) * 64) : 0;

    f32x4 acc[NI][4] = {};

    for (int kt = 0; kt < K; kt += 32) {
        __syncthreads();
        gl2lds(Aga + kt, lA0);
        gl2lds(Agb + kt, lA1);
        gl2lds(Bga + kt, lB0);
        if constexpr (BN == 128) gl2lds(Bgb + kt, lB1);
        __syncthreads();
        bf16x8 af[NI], bfr[4];
#pragma unroll
        for (int i = 0; i < NI; i++) af[i] = *(const bf16x8*)(&As[(WM + i * 16 + lane15) * 32 + quad * 8]);
#pragma unroll
        for (int j = 0; j < 4; j++) bfr[j] = *(const bf16x8*)(&Bs[(WN + j * 16 + lane15) * 32 + quad * 8]);
#pragma unroll
        for (int i = 0; i < NI; i++)
#pragma unroll
            for (int j = 0; j < 4; j++)
                acc[i][j] = __builtin_amdgcn_mfma_f32_16x16x32_bf16(af[i], bfr[j], acc[i][j], 0, 0, 0);
    }

#pragma unroll
    for (int i = 0; i < NI; i++) {
        int mbase = m0 + WM + i * 16 + quad * 4;
#pragma unroll
        for (int j = 0; j < 4; j++) {
            int n = n0 + WN + j * 16 + lane15;
            float bv = bias[n];
#pragma unroll
            for (int r = 0; r < 4; r++) {
                float v = acc[i][j][r] + bv;
                int m = mbase + r;
                if constexpr (MODE == 0) {
                    outp[(size_t)m * 1024 + n] = (bf16)v;
                } else {
                    int b = m >> 11, s = m & 2047;
                    int sel = n >> 10, h = (n >> 6) & 15, hd = n & 63;
                    float scl = (sel == 0) ? 0.125f : 1.0f;
                    outp[(size_t)sel * 4194304 +
                         (((size_t)(b * Hh + h) * Ss + s) * HD) + hd] = (bf16)(v * scl);
                }
            }
        }
    }
}

// ---------------- flash attention v2: no barriers, direct global frags ----------
// grid (qt=32, h=16, b=2), 256 thr. Wave w owns q rows qt*64+w*16..+16.
// Q pre-scaled by 0.125; alibi+mask enter via MFMA C operand.
__global__ __launch_bounds__(256, 3)
void attn2(const bf16* __restrict__ Q, const bf16* __restrict__ Kk, const bf16* __restrict__ Vt,
           const float* __restrict__ alibi, const float* __restrict__ mask,
           bf16* __restrict__ outa) {
    int qt = blockIdx.x, h = blockIdx.y, b = blockIdx.z;
    int tid = threadIdx.x, wave = tid >> 6, lane = tid & 63;
    int lane15 = lane & 15, quad = lane >> 4;
    __shared__ __align__(16) bf16 Pt[4][64 * 20];   // per-wave P^T scratch, stride 20
    bf16* Ptw = Pt[wave];

    const bf16* Qb = Q + ((size_t)(b * Hh + h) * Ss + qt * 64 + wave * 16) * HD;
    const bf16* Kb = Kk + (size_t)(b * Hh + h) * Ss * HD;
    const bf16* Vb = Vt + (size_t)(b * Hh + h) * HD * Ss;
    const float* ab = alibi + ((size_t)h * Ss + qt * 64 + wave * 16 + quad * 4) * Ss;
    const float* mb = mask + (size_t)b * Ss;

    bf16x8 qf0 = *(const bf16x8*)(Qb + lane15 * HD + quad * 8);
    bf16x8 qf1 = *(const bf16x8*)(Qb + lane15 * HD + 32 + quad * 8);

    float m_i[4] = {-1e30f, -1e30f, -1e30f, -1e30f}, l_i[4] = {0.f, 0.f, 0.f, 0.f};
    f32x4 O[4] = {};

    for (int kt = 0; kt < Ss; kt += 64) {
        // ---- scores: S = (0.125*Q)K^T + (alibi+mask) via C operand ----
        f32x4 sc[4];
        float mk[4];
#pragma unroll
        for (int j = 0; j < 4; j++) mk[j] = mb[kt + j * 16 + lane15];
#pragma unroll
        for (int j = 0; j < 4; j++) {
            f32x4 ini;
#pragma unroll
            for (int r = 0; r < 4; r++)
                ini[r] = __builtin_nontemporal_load(&ab[(size_t)r * Ss + kt + j * 16 + lane15]) + mk[j];
            const bf16* kp = Kb + (size_t)(kt + j * 16 + lane15) * HD + quad * 8;
            bf16x8 kf0 = *(const bf16x8*)(kp);
            bf16x8 kf1 = *(const bf16x8*)(kp + 32);
            sc[j] = __builtin_amdgcn_mfma_f32_16x16x32_bf16(qf0, kf0, ini, 0, 0, 0);
            sc[j] = __builtin_amdgcn_mfma_f32_16x16x32_bf16(qf1, kf1, sc[j], 0, 0, 0);
        }
        // ---- online softmax (16-lane groups share a q-row) ----
        float alpha[4];
#pragma unroll
        for (int r = 0; r < 4; r++) {
            float v = fmaxf(fmaxf(sc[0][r], sc[1][r]), fmaxf(sc[2][r], sc[3][r]));
#pragma unroll
            for (int d = 1; d < 16; d <<= 1) v = fmaxf(v, __shfl_xor(v, d, 64));
            float mnew = fmaxf(m_i[r], v);
            alpha[r] = __expf(m_i[r] - mnew);
            m_i[r] = mnew;
        }
        float rs[4] = {0.f, 0.f, 0.f, 0.f};
#pragma unroll
        for (int j = 0; j < 4; j++)
#pragma unroll
            for (int r = 0; r < 4; r++) {
                float p = __expf(sc[j][r] - m_i[r]);
                sc[j][r] = p;
                rs[r] += p;
            }
#pragma unroll
        for (int r = 0; r < 4; r++) {
            float v = rs[r];
#pragma unroll
            for (int d = 1; d < 16; d <<= 1) v += __shfl_xor(v, d, 64);
            l_i[r] = l_i[r] * alpha[r] + v;
        }
        // ---- P (C-layout) -> Pt (per-wave LDS, packed b64 writes) ----
#pragma unroll
        for (int j = 0; j < 4; j++) {
            bf16x4 pw;
#pragma unroll
            for (int r = 0; r < 4; r++) pw[r] = (bf16)sc[j][r];
            *(bf16x4*)(&Ptw[(j * 16 + lane15) * 20 + quad * 4]) = pw;
        }
        bf16x8 pf0, pf1;
#pragma unroll
        for (int jj = 0; jj < 8; jj++) {
            pf0[jj] = Ptw[(quad * 8 + jj) * 20 + lane15];
            pf1[jj] = Ptw[(32 + quad * 8 + jj) * 20 + lane15];
        }
        // ---- O = P V, V^T frags direct from global ----
#pragma unroll
        for (int jd = 0; jd < 4; jd++) {
#pragma unroll
            for (int r = 0; r < 4; r++) O[jd][r] *= alpha[r];
            const bf16* vp = Vb + (size_t)(jd * 16 + lane15) * Ss + kt + quad * 8;
            bf16x8 vf0 = *(const bf16x8*)(vp);
            bf16x8 vf1 = *(const bf16x8*)(vp + 32);
            O[jd] = __builtin_amdgcn_mfma_f32_16x16x32_bf16(pf0, vf0, O[jd], 0, 0, 0);
            O[jd] = __builtin_amdgcn_mfma_f32_16x16x32_bf16(pf1, vf1, O[jd], 0, 0, 0);
        }
    }
    // ---- write [B,S,D] ----
#pragma unroll
    for (int jd = 0; jd < 4; jd++) {
        int d = jd * 16 + lane15;
#pragma unroll
        for (int r = 0; r < 4; r++) {
            int qg = qt * 64 + wave * 16 + quad * 4 + r;
            outa[((size_t)b * Ss + qg) * Dd + h * HD + d] = (bf16)(O[jd][r] / l_i[r]);
        }
    }
}

// ---------------- residual + layernorm ----------------
__global__ void ln_kernel(const float* __restrict__ hidden, const bf16* __restrict__ Y,
                          const float* __restrict__ gamma, const float* __restrict__ beta,
                          float* __restrict__ out) {
    int row = blockIdx.x;
    int tid = threadIdx.x, wave = tid >> 6, lane = tid & 63;
    float x[4];
    float s = 0.f, q = 0.f;
#pragma unroll
    for (int e = 0; e < 4; e++) {
        int col = e * 256 + tid;
        x[e] = hidden[(size_t)row * Dd + col] + (float)Y[(size_t)row * Dd + col];
        s += x[e];
        q += x[e] * x[e];
    }
#pragma unroll
    for (int d = 1; d < 64; d <<= 1) { s += __shfl_xor(s, d, 64); q += __shfl_xor(q, d, 64); }
    __shared__ float sm[4], sq[4];
    if (lane == 0) { sm[wave] = s; sq[wave] = q; }
    __syncthreads();
    float tot = sm[0] + sm[1] + sm[2] + sm[3];
    float totq = sq[0] + sq[1] + sq[2] + sq[3];
    float mu = tot * (1.f / 1024.f);
    float var = totq * (1.f / 1024.f) - mu * mu;
    float rstd = rsqrtf(var + 1e-12f);
#pragma unroll
    for (int e = 0; e < 4; e++) {
        int col = e * 256 + tid;
        out[(size_t)row * Dd + col] = (x[e] - mu) * rstd * gamma[col] + beta[col];
    }
}

// ---------------- launch ----------------
extern "C" void kernel_launch(void* const* d_in, const int* in_sizes, int n_in,
                              void* d_out, int out_size, void* d_ws, size_t ws_size,
                              hipStream_t stream) {
    const float* hidden = (const float*)d_in[0];
    const float* amask  = (const float*)d_in[1];
    const float* alibi  = (const float*)d_in[2];
    const float* Wq = (const float*)d_in[3];
    const float* bq = (const float*)d_in[4];
    const float* Wk = (const float*)d_in[5];
    const float* bk = (const float*)d_in[6];
    const float* Wv = (const float*)d_in[7];
    const float* bv = (const float*)d_in[8];
    const float* Wo = (const float*)d_in[9];
    const float* bo = (const float*)d_in[10];
    const float* ln_g = (const float*)d_in[11];
    const float* ln_b = (const float*)d_in[12];
    float* out = (float*)d_out;

    char* w = (char*)d_ws;
    bf16*  Xb    = (bf16*)(w);                    // 4096x1024        8,388,608
    bf16*  WqT   = (bf16*)(w + 8388608);          // WqT/WkT/WvT contiguous (N=3072)
    bf16*  WkT   = (bf16*)(w + 10485760);
    bf16*  WvT   = (bf16*)(w + 12582912);
    bf16*  WoT   = (bf16*)(w + 14680064);
    float* bQKV  = (float*)(w + 16777216);        // 3072 floats
    bf16*  Qw    = (bf16*)(w + 16793600);         // Q/K/V contiguous, 8,388,608 each
    bf16*  Vw    = (bf16*)(w + 16793600 + 2 * 8388608);
    bf16*  Vtw   = (bf16*)(w + 41959424);
    bf16*  Attn  = (bf16*)(w + 50348032);
    bf16*  Yw    = (bf16*)(w + 58736640);
    // total 67,125,248 B

    cvt_f32_bf16<<<4096, 256, 0, stream>>>(hidden, Xb, Mm * Dd / 4);
    wtrans<<<dim3(16, 16, 4), 256, 0, stream>>>(Wq, Wk, Wv, Wo, WqT, WkT, WvT, WoT);
    bcat<<<12, 256, 0, stream>>>(bq, bk, bv, bQKV);

    gemm2<128, 1><<<dim3(32, 24), 256, 0, stream>>>(Xb, WqT, bQKV, Qw);  // QKV merged

    vtrans<<<dim3(32, 16, 2), 256, 0, stream>>>(Vw, Vtw);

    attn2<<<dim3(32, 16, 2), 256, 0, stream>>>(Qw, Qw + 4194304, Vtw, alibi, amask, Attn);

    gemm2<64, 0><<<dim3(32, 16), 256, 0, stream>>>(Attn, WoT, bo, Yw);

    ln_kernel<<<4096, 256, 0, stream>>>(hidden, Yw, ln_g, ln_b, out);
}

// Round 3
// 685.109 us; speedup vs baseline: 1.0006x; 1.0006x over previous
//
#include <hip/hip_runtime.h>

#define Bb 2
#define Ss 2048
#define Dd 1024
#define Hh 16
#define HD 64
#define Mm (Bb*Ss)   // 4096

typedef __bf16 bf16;
typedef __bf16 bf16x8 __attribute__((ext_vector_type(8)));
typedef __bf16 bf16x4 __attribute__((ext_vector_type(4)));
typedef float f32x4 __attribute__((ext_vector_type(4)));

// async global->LDS 16B copy (m97 pattern): LDS dest = wave-uniform base + lane*16
__device__ __forceinline__ void gl2lds(const bf16* g, bf16* l) {
    __builtin_amdgcn_global_load_lds((const __attribute__((address_space(1))) unsigned int*)g,
                                     (__attribute__((address_space(3))) unsigned int*)l, 16, 0, 0);
}

// ---------------- prep: fp32 -> bf16 cast ----------------
__global__ void cvt_f32_bf16(const float* __restrict__ in, bf16* __restrict__ out, int n4) {
    int i = blockIdx.x * blockDim.x + threadIdx.x;
    if (i < n4) {
        float4 v = *(const float4*)(in + i * 4);
        out[i*4+0] = (bf16)v.x; out[i*4+1] = (bf16)v.y;
        out[i*4+2] = (bf16)v.z; out[i*4+3] = (bf16)v.w;
    }
}

// ---------------- prep: W [K,N] fp32 -> Wt [N,K] bf16 ----------------
__global__ void wtrans(const float* __restrict__ W0, const float* __restrict__ W1,
                       const float* __restrict__ W2, const float* __restrict__ W3,
                       bf16* __restrict__ O0, bf16* __restrict__ O1,
                       bf16* __restrict__ O2, bf16* __restrict__ O3) {
    const float* W = (blockIdx.z == 0) ? W0 : (blockIdx.z == 1) ? W1 : (blockIdx.z == 2) ? W2 : W3;
    bf16* O = (blockIdx.z == 0) ? O0 : (blockIdx.z == 1) ? O1 : (blockIdx.z == 2) ? O2 : O3;
    __shared__ bf16 t[64][65];
    int k0 = blockIdx.x * 64, n0 = blockIdx.y * 64;
    for (int c = threadIdx.x; c < 4096; c += 256) {
        int r = c >> 6, cc = c & 63;
        t[r][cc] = (bf16)W[(k0 + r) * Dd + n0 + cc];
    }
    __syncthreads();
    for (int c = threadIdx.x; c < 4096; c += 256) {
        int r = c >> 6, cc = c & 63;
        O[(n0 + r) * Dd + k0 + cc] = t[cc][r];
    }
}

// ---------------- prep: concat biases ----------------
__global__ void bcat(const float* __restrict__ bq, const float* __restrict__ bk,
                     const float* __restrict__ bv, float* __restrict__ o) {
    int i = blockIdx.x * 256 + threadIdx.x;
    const float* s = (i < 1024) ? bq : (i < 2048) ? bk : bv;
    o[i] = s[i & 1023];
}

// ---------------- prep: V [b,h,s,d] -> Vt [b,h,d,s] ----------------
__global__ void vtrans(const bf16* __restrict__ Vw, bf16* __restrict__ Vt) {
    int st = blockIdx.x, h = blockIdx.y, b = blockIdx.z;
    __shared__ bf16 t[64][65];
    const bf16* src = Vw + ((size_t)(b * Hh + h) * Ss + st * 64) * HD;
    bf16* dst = Vt + (size_t)(b * Hh + h) * HD * Ss + st * 64;
    for (int c = threadIdx.x; c < 4096; c += 256) {
        int r = c >> 6, cc = c & 63;
        t[r][cc] = src[r * HD + cc];
    }
    __syncthreads();
    for (int c = threadIdx.x; c < 4096; c += 256) {
        int r = c >> 6, cc = c & 63;
        dst[(size_t)r * Ss + cc] = t[cc][r];
    }
}

// ---------------- GEMM: C[M,N] = A[M,K]*Bt[N,K]^T + bias, async LDS staging ----
// BM=128, BK=32. MODE 0: plain out [M,1024]. MODE 1: N=3072 merged QKV ->
// [b,h,s,hd] per sel, Q scaled by 0.125*log2(e) (softmax runs in exp2 domain).
template<int BN, int MODE>
__global__ __launch_bounds__(256, 2)
void gemm2(const bf16* __restrict__ A, const bf16* __restrict__ Bt,
           const float* __restrict__ bias, bf16* __restrict__ outp) {
    const int K = 1024;
    __shared__ __align__(16) bf16 As[128 * 32];
    __shared__ __align__(16) bf16 Bs[BN * 32];
    int tid = threadIdx.x, wave = tid >> 6, lane = tid & 63;
    int lane15 = lane & 15, quad = lane >> 4;
    int m0 = blockIdx.x * 128, n0 = blockIdx.y * BN;
    int sr = lane >> 2, sc8 = (lane & 3) * 8;

    const bf16* Aga = A + (size_t)(m0 + wave * 32 + sr) * K + sc8;
    const bf16* Agb = Aga + (size_t)16 * K;
    bf16* lA0 = As + (wave * 32) * 32;
    bf16* lA1 = As + (wave * 32 + 16) * 32;

    const bf16* Bga; const bf16* Bgb = nullptr;
    bf16* lB0; bf16* lB1 = nullptr;
    if constexpr (BN == 128) {
        Bga = Bt + (size_t)(n0 + wave * 32 + sr) * K + sc8;
        Bgb = Bga + (size_t)16 * K;
        lB0 = Bs + (wave * 32) * 32;
        lB1 = Bs + (wave * 32 + 16) * 32;
    } else {
        Bga = Bt + (size_t)(n0 + wave * 16 + sr) * K + sc8;
        lB0 = Bs + (wave * 16) * 32;
    }

    constexpr int NI = (BN == 128) ? 4 : 2;
    const int WM = (BN == 128) ? ((wave >> 1) * 64) : (wave * 32);
    const int WN = (BN == 128) ? ((wave & 1) * 64) : 0;

    f32x4 acc[NI][4] = {};

    for (int kt = 0; kt < K; kt += 32) {
        __syncthreads();
        gl2lds(Aga + kt, lA0);
        gl2lds(Agb + kt, lA1);
        gl2lds(Bga + kt, lB0);
        if constexpr (BN == 128) gl2lds(Bgb + kt, lB1);
        __syncthreads();
        bf16x8 af[NI], bfr[4];
#pragma unroll
        for (int i = 0; i < NI; i++) af[i] = *(const bf16x8*)(&As[(WM + i * 16 + lane15) * 32 + quad * 8]);
#pragma unroll
        for (int j = 0; j < 4; j++) bfr[j] = *(const bf16x8*)(&Bs[(WN + j * 16 + lane15) * 32 + quad * 8]);
#pragma unroll
        for (int i = 0; i < NI; i++)
#pragma unroll
            for (int j = 0; j < 4; j++)
                acc[i][j] = __builtin_amdgcn_mfma_f32_16x16x32_bf16(af[i], bfr[j], acc[i][j], 0, 0, 0);
    }

#pragma unroll
    for (int i = 0; i < NI; i++) {
        int mbase = m0 + WM + i * 16 + quad * 4;
#pragma unroll
        for (int j = 0; j < 4; j++) {
            int n = n0 + WN + j * 16 + lane15;
            float bv = bias[n];
#pragma unroll
            for (int r = 0; r < 4; r++) {
                float v = acc[i][j][r] + bv;
                int m = mbase + r;
                if constexpr (MODE == 0) {
                    outp[(size_t)m * 1024 + n] = (bf16)v;
                } else {
                    int b = m >> 11, s = m & 2047;
                    int sel = n >> 10, h = (n >> 6) & 15, hd = n & 63;
                    float scl = (sel == 0) ? 0.18033688f : 1.0f;  // 0.125 * log2(e)
                    outp[(size_t)sel * 4194304 +
                         (((size_t)(b * Hh + h) * Ss + s) * HD) + hd] = (bf16)(v * scl);
                }
            }
        }
    }
}

// ---------------- flash attention v3 ----------------
// grid (qt=32, h=16), 256 thr, both batches fused per block (alibi fetched ONCE).
// Fixed-m softmax in exp2 domain (scores bounded); l via ones-MFMA (C-layout rowsums).
// Alibi register-pipelined with prefetch distance 1. No __syncthreads anywhere.
__global__ __launch_bounds__(256, 2)
void attn3(const bf16* __restrict__ Q, const bf16* __restrict__ Kk, const bf16* __restrict__ Vt,
           const float* __restrict__ alibi, const float* __restrict__ mask,
           bf16* __restrict__ outa) {
    const int qt = blockIdx.x, h = blockIdx.y;
    const int tid = threadIdx.x, wave = tid >> 6, lane = tid & 63;
    const int lane15 = lane & 15, quad = lane >> 4;
    __shared__ __align__(16) bf16 Pt[4][16 * 72];   // per-wave P row-major, pad 72
    bf16* Ptw = Pt[wave];

    const int qrow = qt * 64 + wave * 16;           // this wave's 16 q rows
    const float* ab = alibi + ((size_t)h * Ss + qrow + quad * 4) * Ss;

    bf16x8 qf[2][2];
    const bf16* Kb[2]; const bf16* Vb[2];
#pragma unroll
    for (int b = 0; b < 2; b++) {
        const bf16* Qb = Q + ((size_t)(b * Hh + h) * Ss + qrow) * HD;
        qf[b][0] = *(const bf16x8*)(Qb + lane15 * HD + quad * 8);
        qf[b][1] = *(const bf16x8*)(Qb + lane15 * HD + 32 + quad * 8);
        Kb[b] = Kk + (size_t)(b * Hh + h) * Ss * HD;
        Vb[b] = Vt + (size_t)(b * Hh + h) * HD * Ss;
    }
    f32x4 O[2][4] = {};
    f32x4 L[2] = {};
    const bf16 one = (bf16)1.0f;
    const bf16x8 on8 = {one, one, one, one, one, one, one, one};

    f32x4 alA[4], alB[4];

    auto loadAl = [&](int kt, f32x4 (&al)[4]) {
#pragma unroll
        for (int j = 0; j < 4; j++) {
            const float* ap = ab + kt + j * 16 + lane15;
            f32x4 a;
#pragma unroll
            for (int r = 0; r < 4; r++) a[r] = ap[(size_t)r * Ss];
            al[j] = a;
        }
    };

    auto body = [&](int kt, f32x4 (&al)[4]) {
#pragma unroll
        for (int b = 0; b < 2; b++) {
            // K frags (B-operand layout) direct from global
            bf16x8 kfr[4][2];
#pragma unroll
            for (int j = 0; j < 4; j++) {
                const bf16* kp = Kb[b] + (size_t)(kt + j * 16 + lane15) * HD + quad * 8;
                kfr[j][0] = *(const bf16x8*)(kp);
                kfr[j][1] = *(const bf16x8*)(kp + 32);
            }
            // V^T frags issued early, consumed at section end
            bf16x8 vfr[4][2];
#pragma unroll
            for (int jd = 0; jd < 4; jd++) {
                const bf16* vp = Vb[b] + (size_t)(jd * 16 + lane15) * Ss + kt + quad * 8;
                vfr[jd][0] = *(const bf16x8*)(vp);
                vfr[jd][1] = *(const bf16x8*)(vp + 32);
            }
            // scores in exp2 domain: (alibi+mask)*log2e enters via C operand
            f32x4 sc[4];
#pragma unroll
            for (int j = 0; j < 4; j++) {
                float mk = mask[(size_t)b * Ss + kt + j * 16 + lane15];
                f32x4 ini;
#pragma unroll
                for (int r = 0; r < 4; r++) ini[r] = (al[j][r] + mk) * 1.44269504f;
                sc[j] = __builtin_amdgcn_mfma_f32_16x16x32_bf16(qf[b][0], kfr[j][0], ini, 0, 0, 0);
                sc[j] = __builtin_amdgcn_mfma_f32_16x16x32_bf16(qf[b][1], kfr[j][1], sc[j], 0, 0, 0);
            }
            // P = 2^sc, C-layout -> row-major LDS -> A-layout b128 reads
#pragma unroll
            for (int j = 0; j < 4; j++)
#pragma unroll
                for (int r = 0; r < 4; r++)
                    Ptw[(quad * 4 + r) * 72 + j * 16 + lane15] = (bf16)exp2f(sc[j][r]);
            bf16x8 pf0 = *(const bf16x8*)(&Ptw[lane15 * 72 + quad * 8]);
            bf16x8 pf1 = *(const bf16x8*)(&Ptw[lane15 * 72 + 32 + quad * 8]);
            // denominator rowsums via ones-MFMA (same C-layout as O)
            L[b] = __builtin_amdgcn_mfma_f32_16x16x32_bf16(pf0, on8, L[b], 0, 0, 0);
            L[b] = __builtin_amdgcn_mfma_f32_16x16x32_bf16(pf1, on8, L[b], 0, 0, 0);
#pragma unroll
            for (int jd = 0; jd < 4; jd++) {
                O[b][jd] = __builtin_amdgcn_mfma_f32_16x16x32_bf16(pf0, vfr[jd][0], O[b][jd], 0, 0, 0);
                O[b][jd] = __builtin_amdgcn_mfma_f32_16x16x32_bf16(pf1, vfr[jd][1], O[b][jd], 0, 0, 0);
            }
        }
    };

    loadAl(0, alA);
    for (int kt = 0; kt < Ss; kt += 128) {
        loadAl(kt + 64, alB);          // prefetch next tile's alibi
        body(kt, alA);
        loadAl(kt + 128 < Ss ? kt + 128 : 0, alA);
        body(kt + 64, alB);
    }

#pragma unroll
    for (int b = 0; b < 2; b++)
#pragma unroll
        for (int jd = 0; jd < 4; jd++) {
            int d = jd * 16 + lane15;
#pragma unroll
            for (int r = 0; r < 4; r++) {
                int qg = qrow + quad * 4 + r;
                outa[((size_t)b * Ss + qg) * Dd + h * HD + d] = (bf16)(O[b][jd][r] / L[b][r]);
            }
        }
}

// ---------------- residual + layernorm ----------------
__global__ void ln_kernel(const float* __restrict__ hidden, const bf16* __restrict__ Y,
                          const float* __restrict__ gamma, const float* __restrict__ beta,
                          float* __restrict__ out) {
    int row = blockIdx.x;
    int tid = threadIdx.x, wave = tid >> 6, lane = tid & 63;
    float x[4];
    float s = 0.f, q = 0.f;
#pragma unroll
    for (int e = 0; e < 4; e++) {
        int col = e * 256 + tid;
        x[e] = hidden[(size_t)row * Dd + col] + (float)Y[(size_t)row * Dd + col];
        s += x[e];
        q += x[e] * x[e];
    }
#pragma unroll
    for (int d = 1; d < 64; d <<= 1) { s += __shfl_xor(s, d, 64); q += __shfl_xor(q, d, 64); }
    __shared__ float sm[4], sq[4];
    if (lane == 0) { sm[wave] = s; sq[wave] = q; }
    __syncthreads();
    float tot = sm[0] + sm[1] + sm[2] + sm[3];
    float totq = sq[0] + sq[1] + sq[2] + sq[3];
    float mu = tot * (1.f / 1024.f);
    float var = totq * (1.f / 1024.f) - mu * mu;
    float rstd = rsqrtf(var + 1e-12f);
#pragma unroll
    for (int e = 0; e < 4; e++) {
        int col = e * 256 + tid;
        out[(size_t)row * Dd + col] = (x[e] - mu) * rstd * gamma[col] + beta[col];
    }
}

// ---------------- launch ----------------
extern "C" void kernel_launch(void* const* d_in, const int* in_sizes, int n_in,
                              void* d_out, int out_size, void* d_ws, size_t ws_size,
                              hipStream_t stream) {
    const float* hidden = (const float*)d_in[0];
    const float* amask  = (const float*)d_in[1];
    const float* alibi  = (const float*)d_in[2];
    const float* Wq = (const float*)d_in[3];
    const float* bq = (const float*)d_in[4];
    const float* Wk = (const float*)d_in[5];
    const float* bk = (const float*)d_in[6];
    const float* Wv = (const float*)d_in[7];
    const float* bv = (const float*)d_in[8];
    const float* Wo = (const float*)d_in[9];
    const float* bo = (const float*)d_in[10];
    const float* ln_g = (const float*)d_in[11];
    const float* ln_b = (const float*)d_in[12];
    float* out = (float*)d_out;

    char* w = (char*)d_ws;
    bf16*  Xb    = (bf16*)(w);                    // 4096x1024        8,388,608
    bf16*  WqT   = (bf16*)(w + 8388608);          // WqT/WkT/WvT contiguous (N=3072)
    bf16*  WkT   = (bf16*)(w + 10485760);
    bf16*  WvT   = (bf16*)(w + 12582912);
    bf16*  WoT   = (bf16*)(w + 14680064);
    float* bQKV  = (float*)(w + 16777216);        // 3072 floats
    bf16*  Qw    = (bf16*)(w + 16793600);         // Q/K/V contiguous, 8,388,608 each
    bf16*  Vw    = (bf16*)(w + 16793600 + 2 * 8388608);
    bf16*  Vtw   = (bf16*)(w + 41959424);
    bf16*  Attn  = (bf16*)(w + 50348032);
    bf16*  Yw    = (bf16*)(w + 58736640);
    // total 67,125,248 B

    cvt_f32_bf16<<<4096, 256, 0, stream>>>(hidden, Xb, Mm * Dd / 4);
    wtrans<<<dim3(16, 16, 4), 256, 0, stream>>>(Wq, Wk, Wv, Wo, WqT, WkT, WvT, WoT);
    bcat<<<12, 256, 0, stream>>>(bq, bk, bv, bQKV);

    gemm2<128, 1><<<dim3(32, 24), 256, 0, stream>>>(Xb, WqT, bQKV, Qw);  // QKV merged

    vtrans<<<dim3(32, 16, 2), 256, 0, stream>>>(Vw, Vtw);

    attn3<<<dim3(32, 16), 256, 0, stream>>>(Qw, Qw + 4194304, Vtw, alibi, amask, Attn);

    gemm2<64, 0><<<dim3(32, 16), 256, 0, stream>>>(Attn, WoT, bo, Yw);

    ln_kernel<<<4096, 256, 0, stream>>>(hidden, Yw, ln_g, ln_b, out);
}